// Round 1
// 273.895 us; speedup vs baseline: 1.1039x; 1.1039x over previous
//
#include <hip/hip_runtime.h>
#include <hip/hip_bf16.h>
#include <math.h>

#define HDIM 128
#define PAD 64   // max degree slots per node; P(Poisson(16) >= 64) ~ 2e-18
typedef unsigned short ushort_t;
typedef unsigned int uint_t;
typedef __attribute__((ext_vector_type(8))) short bf16x8;
typedef __attribute__((ext_vector_type(4))) float f32x4;
typedef __attribute__((ext_vector_type(2))) float v2f;

__device__ __forceinline__ float wave_allreduce(float v){
  #pragma unroll
  for (int o = 1; o < 64; o <<= 1) v += __shfl_xor(v, o);
  return v;
}

__device__ __forceinline__ ushort_t f2bf(float f){
  uint_t u = __float_as_uint(f);
  uint_t r = (u + 0x7fffu + ((u >> 16) & 1u)) >> 16;
  return (ushort_t)r;
}

// unpack 2 packed bf16 (lo,hi) -> v2f
__device__ __forceinline__ v2f bf2(uint_t u){
  v2f r;
  r.x = __uint_as_float(u << 16);
  r.y = __uint_as_float(u & 0xffff0000u);
  return r;
}

// pack W2t[c][k] bf16 (c<128 P-w, c<256 Q-w, 256/257 u/v, else 0); tail blocks zero cnt
__global__ __launch_bounds__(128) void k_wpack(const float* __restrict__ Wg,
    const float* __restrict__ Wf, ushort_t* __restrict__ W2t,
    int* __restrict__ cnt, int N){
  int b = blockIdx.x;
  int k = threadIdx.x;
  if (b < 272){
    float val;
    if (b < 128)       val = Wg[(size_t)(b >> 5) * 8192 + k * 32 + (b & 31)];
    else if (b < 256){ int c2 = b - 128;
                       val = Wg[(size_t)(c2 >> 5) * 8192 + (k + 128) * 32 + (c2 & 31)]; }
    else if (b == 256) val = Wf[k];
    else if (b == 257) val = Wf[128 + k];
    else               val = 0.f;
    W2t[(size_t)b * 128 + k] = f2bf(val);
  } else {
    int i = (b - 272) * 128 + k;
    if (i < N) cnt[i] = 0;
  }
}

// Fused dispatch: blocks [0,GB) = MFMA GEMM (col-split 2x: each wave 16 rows x
// 8-9 tiles); blocks [GB, GB+FB) = XCD-partitioned CSR fill. Independent work
// overlapping MFMA/latency pipe with atomic/memory pipe.
__global__ __launch_bounds__(256) void k_gemmfill(const float* __restrict__ x,
    const ushort_t* __restrict__ W2t, const float* __restrict__ weight,
    ushort_t* __restrict__ Pb, ushort_t* __restrict__ Qb,
    float* __restrict__ v, float2* __restrict__ uw2,
    const int* __restrict__ src, const int* __restrict__ dst,
    int* __restrict__ cnt, int* __restrict__ es,
    int N, int E, int GB){
  if ((int)blockIdx.x < GB){
    // ---- GEMM part ----
    int wid = __builtin_amdgcn_readfirstlane(threadIdx.x >> 6);
    int lane = threadIdx.x & 63;
    int quad = lane >> 4, col = lane & 15;
    int strip = blockIdx.x * 2 + (wid >> 1);
    int half = wid & 1;
    int n_base = strip * 16;
    if (n_base >= N) return;
    int tbeg = half * 8;
    int ntile = half ? 9 : 8;          // half 0: ct 0..7 (P); half 1: ct 8..16 (Q + uv)
    f32x4 acc[9];
    #pragma unroll
    for (int t = 0; t < 9; ++t) acc[t] = (f32x4){0.f, 0.f, 0.f, 0.f};
    int row = n_base + col;
    int rowc = row < N ? row : N - 1;
    const float* xr = x + (size_t)rowc * HDIM + quad * 8;
    #pragma unroll
    for (int kk = 0; kk < 4; ++kk){
      float4 a0 = *(const float4*)(xr + kk * 32);
      float4 a1 = *(const float4*)(xr + kk * 32 + 4);
      bf16x8 af;
      af[0] = (short)f2bf(a0.x); af[1] = (short)f2bf(a0.y);
      af[2] = (short)f2bf(a0.z); af[3] = (short)f2bf(a0.w);
      af[4] = (short)f2bf(a1.x); af[5] = (short)f2bf(a1.y);
      af[6] = (short)f2bf(a1.z); af[7] = (short)f2bf(a1.w);
      const ushort_t* wb = W2t + (size_t)(tbeg * 16) * 128 + (size_t)col * 128 + kk * 32 + quad * 8;
      #pragma unroll
      for (int t = 0; t < 9; ++t){
        if (t < ntile){
          bf16x8 bfr = *(const bf16x8*)(wb + (size_t)t * 16 * 128);
          acc[t] = __builtin_amdgcn_mfma_f32_16x16x32_bf16(af, bfr, acc[t], 0, 0, 0);
        }
      }
    }
    #pragma unroll
    for (int t = 0; t < 8; ++t){
      int ct = tbeg + t;
      int c = ct * 16 + col;
      #pragma unroll
      for (int r = 0; r < 4; ++r){
        int n = n_base + quad * 4 + r;
        if (n < N){
          ushort_t valb = f2bf(acc[t][r]);
          if (c < 128) Pb[(size_t)n * HDIM + c] = valb;
          else         Qb[(size_t)n * HDIM + (c - 128)] = valb;
        }
      }
    }
    if (half){
      #pragma unroll
      for (int r = 0; r < 4; ++r){
        int n = n_base + quad * 4 + r;
        if (n < N){
          float val = acc[8][r];
          if (col == 0)      uw2[n] = make_float2(val, weight[n]);
          else if (col == 1) v[n] = val;
        }
      }
    }
  } else {
    // ---- fill part: XCD-partitioned padded-CSR build ----
    int bi = blockIdx.x - GB;
    int part = bi & 7;
    int nch = (gridDim.x - GB) >> 3;
    int chunk = bi >> 3;
    int Npp = (N + 7) >> 3;
    int lo = part * Npp;
    int hi = lo + Npp; if (hi > N) hi = N;
    int stride = nch * 256;
    for (int e = chunk * 256 + threadIdx.x; e < E; e += stride){
      int d = dst[e];
      if (d >= lo && d < hi){
        int c = atomicAdd(&cnt[d], 1);
        if (c < PAD) es[(size_t)d * PAD + c] = src[e];
      }
    }
  }
}

// g-BN stats (+ lane-parallel f-BN stats): XCD-partitioned nodes (matches fill
// partition's XCD so es/cnt/Q/v are L2-local), cross-node prefetch, unroll 8,
// block-level partial reduction.
__global__ __launch_bounds__(256) void k_gstats(const ushort_t* __restrict__ Pb,
    const ushort_t* __restrict__ Qb, const float* __restrict__ v,
    const float2* __restrict__ uw2, const int* __restrict__ es,
    const int* __restrict__ cnt, float* __restrict__ pstatG, int N, int GB){
  int lane = threadIdx.x & 63;
  int wid = __builtin_amdgcn_readfirstlane(threadIdx.x >> 6);
  int part = ((int)blockIdx.x - GB) & 7;          // same XCD as fill partition
  int Npp = (N + 7) >> 3;
  int lo = part * Npp;
  int hi = lo + Npp; if (hi > N) hi = N;
  int step = (gridDim.x >> 3) << 2;               // waves per partition
  const uint_t* Pu = (const uint_t*)Pb;
  const uint_t* Qu = (const uint_t*)Qb;
  v2f gs = {0.f, 0.f}, gq = {0.f, 0.f};
  float fs = 0.f, fq = 0.f;
  int n = lo + ((blockIdx.x >> 3) << 2) + wid;
  // prefetch node A
  int dnA = 0, sjA = 0; uint_t qA = 0; float vA = 0.f;
  if (n < hi){
    dnA = cnt[n];
    sjA = es[(size_t)n * PAD + lane];
    qA  = Qu[(size_t)n * 64 + lane];
    vA  = v[n];
  }
  while (n < hi){
    int nn = n + step;
    int dnB = 0, sjB = 0; uint_t qB = 0; float vB = 0.f;
    if (nn < hi){                                  // prefetch node B during A's work
      dnB = cnt[nn];
      sjB = es[(size_t)nn * PAD + lane];
      qB  = Qu[(size_t)nn * 64 + lane];
      vB  = v[nn];
    }
    int dn = dnA < PAD ? dnA : PAD;
    int sj = sjA;
    if (lane < dn){
      float2 uw = uw2[sj];
      float t = uw.x + vA;
      fs += t; fq = fmaf(t, t, fq);
    }
    v2f q = bf2(qA);
    int j = 0;
#define GSTAT(p) { v2f y = bf2(p) + q; gs += y; \
                   gq.x = fmaf(y.x, y.x, gq.x); gq.y = fmaf(y.y, y.y, gq.y); }
    for (; j + 7 < dn; j += 8){
      int s0=__shfl(sj,j),   s1=__shfl(sj,j+1), s2=__shfl(sj,j+2), s3=__shfl(sj,j+3);
      int s4=__shfl(sj,j+4), s5=__shfl(sj,j+5), s6=__shfl(sj,j+6), s7=__shfl(sj,j+7);
      uint_t p0=Pu[(size_t)s0*64+lane], p1=Pu[(size_t)s1*64+lane];
      uint_t p2=Pu[(size_t)s2*64+lane], p3=Pu[(size_t)s3*64+lane];
      uint_t p4=Pu[(size_t)s4*64+lane], p5=Pu[(size_t)s5*64+lane];
      uint_t p6=Pu[(size_t)s6*64+lane], p7=Pu[(size_t)s7*64+lane];
      GSTAT(p0) GSTAT(p1) GSTAT(p2) GSTAT(p3)
      GSTAT(p4) GSTAT(p5) GSTAT(p6) GSTAT(p7)
    }
    for (; j + 3 < dn; j += 4){
      int s0=__shfl(sj,j), s1=__shfl(sj,j+1), s2=__shfl(sj,j+2), s3=__shfl(sj,j+3);
      uint_t p0=Pu[(size_t)s0*64+lane], p1=Pu[(size_t)s1*64+lane];
      uint_t p2=Pu[(size_t)s2*64+lane], p3=Pu[(size_t)s3*64+lane];
      GSTAT(p0) GSTAT(p1) GSTAT(p2) GSTAT(p3)
    }
    for (; j < dn; ++j){
      int s0 = __shfl(sj, j);
      uint_t p0 = Pu[(size_t)s0*64+lane];
      GSTAT(p0)
    }
#undef GSTAT
    n = nn; dnA = dnB; sjA = sjB; qA = qB; vA = vB;
  }
  fs = wave_allreduce(fs); fq = wave_allreduce(fq);
  __shared__ float red[4][258];
  red[wid][2*lane]       = gs.x; red[wid][2*lane+1]   = gs.y;
  red[wid][128+2*lane]   = gq.x; red[wid][129+2*lane] = gq.y;
  if (lane == 0){ red[wid][256] = fs; red[wid][257] = fq; }
  __syncthreads();
  for (int c = threadIdx.x; c < 258; c += 256)
    pstatG[(size_t)blockIdx.x * 258 + c] = red[0][c] + red[1][c] + red[2][c] + red[3][c];
}

// fused column-reduce + finalize for g/f BN: block j<128 -> channel j; block 128 -> f
__global__ __launch_bounds__(256) void k_redfin1(const float* __restrict__ pstatG,
    int NB, const float* __restrict__ g_gamma, const float* __restrict__ g_beta,
    const float* __restrict__ f_gamma, const float* __restrict__ f_beta,
    float* __restrict__ fin, long long E){
  int j = blockIdx.x;
  int c1 = (j < 128) ? j : 256;
  int c2 = (j < 128) ? 128 + j : 257;
  double s1 = 0, s2 = 0;
  for (int b = threadIdx.x; b < NB; b += 256){
    const float* pb = pstatG + (size_t)b * 258;
    s1 += (double)pb[c1]; s2 += (double)pb[c2];
  }
  __shared__ double m1[256], m2[256];
  m1[threadIdx.x] = s1; m2[threadIdx.x] = s2;
  __syncthreads();
  for (int o = 128; o; o >>= 1){
    if (threadIdx.x < o){ m1[threadIdx.x] += m1[threadIdx.x + o];
                          m2[threadIdx.x] += m2[threadIdx.x + o]; }
    __syncthreads();
  }
  if (threadIdx.x == 0){
    double m = m1[0] / (double)E;
    double var = m2[0] / (double)E - m * m;
    if (j < 128){
      float sc = (float)((double)g_gamma[j] / sqrt(var + 1e-5));
      fin[2 + j] = sc; fin[130 + j] = g_beta[j] - (float)m * sc;
    } else {
      float sc = (float)((double)f_gamma[0] / sqrt(var + 1e-5));
      fin[0] = sc; fin[1] = f_beta[0] - (float)m * sc;
    }
  }
}

// message pass: XCD-partitioned nodes, cross-node prefetch, unroll 8, deferred
// attention normalization (allreduce off the critical path; single scale at end)
__global__ __launch_bounds__(256) void k_msg(const ushort_t* __restrict__ Pb,
    const ushort_t* __restrict__ Qb, const float* __restrict__ v,
    const float2* __restrict__ uw2, const int* __restrict__ es,
    const int* __restrict__ cnt, const float* __restrict__ fin,
    float* __restrict__ h, float* __restrict__ pstatH, int N, int GB){
  int lane = threadIdx.x & 63;
  int wid = __builtin_amdgcn_readfirstlane(threadIdx.x >> 6);
  int part = ((int)blockIdx.x - GB) & 7;
  int Npp = (N + 7) >> 3;
  int lo = part * Npp;
  int hi = lo + Npp; if (hi > N) hi = N;
  int step = (gridDim.x >> 3) << 2;
  const uint_t* Pu = (const uint_t*)Pb;
  const uint_t* Qu = (const uint_t*)Qb;
  float fsc = fin[0], fsh = fin[1];
  v2f gsc = {fin[2 + 2*lane], fin[3 + 2*lane]};
  v2f gsh = {fin[130 + 2*lane], fin[131 + 2*lane]};
  v2f hs = {0.f, 0.f}, hq = {0.f, 0.f};
  int n = lo + ((blockIdx.x >> 3) << 2) + wid;
  int dnA = 0, sjA = 0; uint_t qA = 0; float vA = 0.f;
  if (n < hi){
    dnA = cnt[n];
    sjA = es[(size_t)n * PAD + lane];
    qA  = Qu[(size_t)n * 64 + lane];
    vA  = v[n];
  }
  while (n < hi){
    int nn = n + step;
    int dnB = 0, sjB = 0; uint_t qB = 0; float vB = 0.f;
    if (nn < hi){
      dnB = cnt[nn];
      sjB = es[(size_t)nn * PAD + lane];
      qB  = Qu[(size_t)nn * 64 + lane];
      vB  = v[nn];
    }
    int dn = dnA < PAD ? dnA : PAD;
    int sj = sjA;
    float wj = 0.f;
    if (lane < dn){
      float2 uw = uw2[sj];
      float tt = fmaf(uw.x + vA, fsc, fsh);
      float sl = tt * __builtin_amdgcn_rcpf(1.f + __expf(-tt));
      wj = uw.y * __expf(sl);
    }
    v2f q = bf2(qA);
    v2f acc = {0.f, 0.f};
    int j = 0;
#define EDGE(p,a) { v2f y = (bf2(p) + q) * gsc + gsh; \
      float e0 = __expf(-y.x), e1 = __expf(-y.y); \
      float d0 = 1.f + e0, d1 = 1.f + e1; \
      float r = __builtin_amdgcn_rcpf(d0 * d1) * a; \
      acc.x = fmaf(y.x * d1, r, acc.x); acc.y = fmaf(y.y * d0, r, acc.y); }
    for (; j + 7 < dn; j += 8){
      int s0=__shfl(sj,j),   s1=__shfl(sj,j+1), s2=__shfl(sj,j+2), s3=__shfl(sj,j+3);
      int s4=__shfl(sj,j+4), s5=__shfl(sj,j+5), s6=__shfl(sj,j+6), s7=__shfl(sj,j+7);
      float a0=__shfl(wj,j),   a1=__shfl(wj,j+1), a2=__shfl(wj,j+2), a3=__shfl(wj,j+3);
      float a4=__shfl(wj,j+4), a5=__shfl(wj,j+5), a6=__shfl(wj,j+6), a7=__shfl(wj,j+7);
      uint_t p0=Pu[(size_t)s0*64+lane], p1=Pu[(size_t)s1*64+lane];
      uint_t p2=Pu[(size_t)s2*64+lane], p3=Pu[(size_t)s3*64+lane];
      uint_t p4=Pu[(size_t)s4*64+lane], p5=Pu[(size_t)s5*64+lane];
      uint_t p6=Pu[(size_t)s6*64+lane], p7=Pu[(size_t)s7*64+lane];
      EDGE(p0,a0) EDGE(p1,a1) EDGE(p2,a2) EDGE(p3,a3)
      EDGE(p4,a4) EDGE(p5,a5) EDGE(p6,a6) EDGE(p7,a7)
    }
    for (; j + 3 < dn; j += 4){
      int s0=__shfl(sj,j), s1=__shfl(sj,j+1), s2=__shfl(sj,j+2), s3=__shfl(sj,j+3);
      float a0=__shfl(wj,j), a1=__shfl(wj,j+1), a2=__shfl(wj,j+2), a3=__shfl(wj,j+3);
      uint_t p0=Pu[(size_t)s0*64+lane], p1=Pu[(size_t)s1*64+lane];
      uint_t p2=Pu[(size_t)s2*64+lane], p3=Pu[(size_t)s3*64+lane];
      EDGE(p0,a0) EDGE(p1,a1) EDGE(p2,a2) EDGE(p3,a3)
    }
    for (; j < dn; ++j){
      int s0 = __shfl(sj, j);
      float a0 = __shfl(wj, j);
      uint_t p0 = Pu[(size_t)s0*64+lane];
      EDGE(p0,a0)
    }
#undef EDGE
    // deferred normalization: h = (sum_j w_j z_j) / (sum_j w_j)
    float sw = wave_allreduce(wj);
    float rs = (dn > 0) ? (1.f / sw) : 0.f;
    acc.x *= rs; acc.y *= rs;
    *(float2*)&h[(size_t)n * 128 + 2*lane] = make_float2(acc.x, acc.y);
    hs += acc; hq += acc * acc;
    n = nn; dnA = dnB; sjA = sjB; qA = qB; vA = vB;
  }
  __shared__ float red[4][256];
  red[wid][2*lane]       = hs.x; red[wid][2*lane+1]   = hs.y;
  red[wid][128+2*lane]   = hq.x; red[wid][129+2*lane] = hq.y;
  __syncthreads();
  int c = threadIdx.x;
  pstatH[(size_t)blockIdx.x * 256 + c] = red[0][c] + red[1][c] + red[2][c] + red[3][c];
}

// fused column-reduce + finalize for node BN: block j -> channel j
__global__ __launch_bounds__(256) void k_redfin2(const float* __restrict__ pstatH,
    int NB, const float* __restrict__ n_gamma, const float* __restrict__ n_beta,
    float* __restrict__ fin, int N){
  int j = blockIdx.x;
  double s1 = 0, s2 = 0;
  for (int b = threadIdx.x; b < NB; b += 256){
    const float* pb = pstatH + (size_t)b * 256;
    s1 += (double)pb[j]; s2 += (double)pb[128 + j];
  }
  __shared__ double m1[256], m2[256];
  m1[threadIdx.x] = s1; m2[threadIdx.x] = s2;
  __syncthreads();
  for (int o = 128; o; o >>= 1){
    if (threadIdx.x < o){ m1[threadIdx.x] += m1[threadIdx.x + o];
                          m2[threadIdx.x] += m2[threadIdx.x + o]; }
    __syncthreads();
  }
  if (threadIdx.x == 0){
    double m = m1[0] / (double)N;
    double var = m2[0] / (double)N - m * m;
    float sc = (float)((double)n_gamma[j] / sqrt(var + 1e-5));
    fin[258 + j] = sc; fin[386 + j] = n_beta[j] - (float)m * sc;
  }
}

__global__ __launch_bounds__(256) void k_out(const float* __restrict__ h,
    const float* __restrict__ x, const float* __restrict__ fin,
    float* __restrict__ out, int total4){
  int i = blockIdx.x * 256 + threadIdx.x;
  if (i >= total4) return;
  const float4* h4 = (const float4*)h; const float4* x4 = (const float4*)x;
  float4 hv = h4[i], xv = x4[i];
  int c = (i * 4) & 127;
  float4 o;
  o.x = fmaf(hv.x, fin[258 + c],     fin[386 + c])     + xv.x;
  o.y = fmaf(hv.y, fin[258 + c + 1], fin[386 + c + 1]) + xv.y;
  o.z = fmaf(hv.z, fin[258 + c + 2], fin[386 + c + 2]) + xv.z;
  o.w = fmaf(hv.w, fin[258 + c + 3], fin[386 + c + 3]) + xv.w;
  ((float4*)out)[i] = o;
}

extern "C" void kernel_launch(void* const* d_in, const int* in_sizes, int n_in,
                              void* d_out, int out_size, void* d_ws, size_t ws_size,
                              hipStream_t stream){
  const float* x       = (const float*)d_in[0];
  const float* weight  = (const float*)d_in[1];
  const int*   src     = (const int*)d_in[2];
  const int*   dst     = (const int*)d_in[3];
  const float* Wf      = (const float*)d_in[4];
  // d_in[5] = bf : cancels inside BatchNorm — unused
  const float* f_gamma = (const float*)d_in[6];
  const float* f_beta  = (const float*)d_in[7];
  const float* Wg      = (const float*)d_in[8];
  // d_in[9] = bg : cancels inside BatchNorm — unused
  const float* g_gamma = (const float*)d_in[10];
  const float* g_beta  = (const float*)d_in[11];
  const float* n_gamma = (const float*)d_in[12];
  const float* n_beta  = (const float*)d_in[13];
  float* out = (float*)d_out;

  int N = in_sizes[0] / HDIM;
  int E = in_sizes[2];

  char* ws = (char*)d_ws;
  size_t off = 0;
  auto alloc = [&](size_t bytes)->char*{
    char* p = ws + off; off = (off + bytes + 255) & ~(size_t)255; return p;
  };
  ushort_t* Pb    = (ushort_t*)alloc((size_t)N * HDIM * 2);
  ushort_t* Qb    = (ushort_t*)alloc((size_t)N * HDIM * 2);
  float* h        = (float*)alloc((size_t)N * HDIM * 4);
  float* v        = (float*)alloc((size_t)N * 4);
  float2* uw2     = (float2*)alloc((size_t)N * 8);
  int* es         = (int*)alloc((size_t)N * PAD * 4);
  ushort_t* W2t   = (ushort_t*)alloc((size_t)272 * 128 * 2);
  int* cnt        = (int*)alloc((size_t)N * 4);
  const int NWB = 2048;              // blocks for gstats/msg (4 waves each)
  const int NB  = NWB;               // one partial row per block now
  float*  pstatG = (float*)alloc((size_t)NB * 258 * 4);
  float*  pstatH = (float*)alloc((size_t)NB * 256 * 4);
  float*  fin    = (float*)alloc(514 * 4);

  int GB = (N + 31) / 32;            // gemm blocks (2 strips of 16 rows each)
  const int FB = 4096;               // fill blocks (8 partitions x 512 chunks)

  k_wpack   <<<272 + (N + 127) / 128, 128, 0, stream>>>(Wg, Wf, W2t, cnt, N);
  k_gemmfill<<<GB + FB, 256, 0, stream>>>(x, W2t, weight, Pb, Qb, v, uw2,
                                          src, dst, cnt, es, N, E, GB);
  k_gstats  <<<NWB, 256, 0, stream>>>(Pb, Qb, v, uw2, es, cnt, pstatG, N, GB);
  k_redfin1 <<<129, 256, 0, stream>>>(pstatG, NB, g_gamma, g_beta, f_gamma, f_beta, fin, (long long)E);
  k_msg     <<<NWB, 256, 0, stream>>>(Pb, Qb, v, uw2, es, cnt, fin, h, pstatH, N, GB);
  k_redfin2 <<<128, 256, 0, stream>>>(pstatH, NB, n_gamma, n_beta, fin, N);
  k_out     <<<(N * HDIM / 4 + 255) / 256, 256, 0, stream>>>(h, x, fin, out, N * HDIM / 4);
}

// Round 2
// 272.921 us; speedup vs baseline: 1.1078x; 1.0036x over previous
//
#include <hip/hip_runtime.h>
#include <hip/hip_bf16.h>
#include <math.h>

#define HDIM 128
#define PAD 64   // max degree slots per node; P(Poisson(16) >= 64) ~ 2e-18
typedef unsigned short ushort_t;
typedef unsigned int uint_t;
typedef __attribute__((ext_vector_type(8))) short bf16x8;
typedef __attribute__((ext_vector_type(4))) float f32x4;
typedef __attribute__((ext_vector_type(2))) float v2f;

__device__ __forceinline__ float wave_allreduce(float v){
  #pragma unroll
  for (int o = 1; o < 64; o <<= 1) v += __shfl_xor(v, o);
  return v;
}

__device__ __forceinline__ ushort_t f2bf(float f){
  uint_t u = __float_as_uint(f);
  uint_t r = (u + 0x7fffu + ((u >> 16) & 1u)) >> 16;
  return (ushort_t)r;
}

// unpack 2 packed bf16 (lo,hi) -> v2f
__device__ __forceinline__ v2f bf2(uint_t u){
  v2f r;
  r.x = __uint_as_float(u << 16);
  r.y = __uint_as_float(u & 0xffff0000u);
  return r;
}

// pack W2t[c][k] bf16 (c<128 P-w, c<256 Q-w, 256/257 u/v, else 0); tail blocks zero cnt
__global__ __launch_bounds__(128) void k_wpack(const float* __restrict__ Wg,
    const float* __restrict__ Wf, ushort_t* __restrict__ W2t,
    int* __restrict__ cnt, int N){
  int b = blockIdx.x;
  int k = threadIdx.x;
  if (b < 272){
    float val;
    if (b < 128)       val = Wg[(size_t)(b >> 5) * 8192 + k * 32 + (b & 31)];
    else if (b < 256){ int c2 = b - 128;
                       val = Wg[(size_t)(c2 >> 5) * 8192 + (k + 128) * 32 + (c2 & 31)]; }
    else if (b == 256) val = Wf[k];
    else if (b == 257) val = Wf[128 + k];
    else               val = 0.f;
    W2t[(size_t)b * 128 + k] = f2bf(val);
  } else {
    int i = (b - 272) * 128 + k;
    if (i < N) cnt[i] = 0;
  }
}

// Fused dispatch: blocks [0,GB) = MFMA GEMM (col-split 2x: each wave 16 rows x
// 8-9 tiles); blocks [GB, GB+FB) = XCD-partitioned CSR fill with 8-deep
// software-pipelined edge scan (batched dst+src loads, batched atomics).
__global__ __launch_bounds__(256) void k_gemmfill(const float* __restrict__ x,
    const ushort_t* __restrict__ W2t, const float* __restrict__ weight,
    ushort_t* __restrict__ Pb, ushort_t* __restrict__ Qb,
    float* __restrict__ v, float2* __restrict__ uw2,
    const int* __restrict__ src, const int* __restrict__ dst,
    int* __restrict__ cnt, int* __restrict__ es,
    int N, int E, int GB){
  if ((int)blockIdx.x < GB){
    // ---- GEMM part ----
    int wid = __builtin_amdgcn_readfirstlane(threadIdx.x >> 6);
    int lane = threadIdx.x & 63;
    int quad = lane >> 4, col = lane & 15;
    int strip = blockIdx.x * 2 + (wid >> 1);
    int half = wid & 1;
    int n_base = strip * 16;
    if (n_base >= N) return;
    int tbeg = half * 8;
    int ntile = half ? 9 : 8;          // half 0: ct 0..7 (P); half 1: ct 8..16 (Q + uv)
    f32x4 acc[9];
    #pragma unroll
    for (int t = 0; t < 9; ++t) acc[t] = (f32x4){0.f, 0.f, 0.f, 0.f};
    int row = n_base + col;
    int rowc = row < N ? row : N - 1;
    const float* xr = x + (size_t)rowc * HDIM + quad * 8;
    #pragma unroll
    for (int kk = 0; kk < 4; ++kk){
      float4 a0 = *(const float4*)(xr + kk * 32);
      float4 a1 = *(const float4*)(xr + kk * 32 + 4);
      bf16x8 af;
      af[0] = (short)f2bf(a0.x); af[1] = (short)f2bf(a0.y);
      af[2] = (short)f2bf(a0.z); af[3] = (short)f2bf(a0.w);
      af[4] = (short)f2bf(a1.x); af[5] = (short)f2bf(a1.y);
      af[6] = (short)f2bf(a1.z); af[7] = (short)f2bf(a1.w);
      const ushort_t* wb = W2t + (size_t)(tbeg * 16) * 128 + (size_t)col * 128 + kk * 32 + quad * 8;
      #pragma unroll
      for (int t = 0; t < 9; ++t){
        if (t < ntile){
          bf16x8 bfr = *(const bf16x8*)(wb + (size_t)t * 16 * 128);
          acc[t] = __builtin_amdgcn_mfma_f32_16x16x32_bf16(af, bfr, acc[t], 0, 0, 0);
        }
      }
    }
    #pragma unroll
    for (int t = 0; t < 8; ++t){
      int ct = tbeg + t;
      int c = ct * 16 + col;
      #pragma unroll
      for (int r = 0; r < 4; ++r){
        int n = n_base + quad * 4 + r;
        if (n < N){
          ushort_t valb = f2bf(acc[t][r]);
          if (c < 128) Pb[(size_t)n * HDIM + c] = valb;
          else         Qb[(size_t)n * HDIM + (c - 128)] = valb;
        }
      }
    }
    if (half){
      #pragma unroll
      for (int r = 0; r < 4; ++r){
        int n = n_base + quad * 4 + r;
        if (n < N){
          float val = acc[8][r];
          if (col == 0)      uw2[n] = make_float2(val, weight[n]);
          else if (col == 1) v[n] = val;
        }
      }
    }
  } else {
    // ---- fill part: XCD-partitioned padded-CSR build, 8-deep pipelined ----
    int bi = blockIdx.x - GB;
    int part = bi & 7;
    int nch = (gridDim.x - GB) >> 3;
    int chunk = bi >> 3;
    int Npp = (N + 7) >> 3;
    int lo = part * Npp;
    int hi = lo + Npp; if (hi > N) hi = N;
    int stride = nch * 256;
    int e = chunk * 256 + threadIdx.x;
#define FILL1(d, s) if ((d) >= lo && (d) < hi){ \
      int c = atomicAdd(&cnt[d], 1); \
      if (c < PAD) es[(size_t)(d) * PAD + c] = (s); }
    for (; e + 7 * stride < E; e += 8 * stride){
      int d0 = dst[e],            d1 = dst[e + stride];
      int d2 = dst[e + 2*stride], d3 = dst[e + 3*stride];
      int d4 = dst[e + 4*stride], d5 = dst[e + 5*stride];
      int d6 = dst[e + 6*stride], d7 = dst[e + 7*stride];
      int s0 = src[e],            s1 = src[e + stride];
      int s2 = src[e + 2*stride], s3 = src[e + 3*stride];
      int s4 = src[e + 4*stride], s5 = src[e + 5*stride];
      int s6 = src[e + 6*stride], s7 = src[e + 7*stride];
      FILL1(d0, s0) FILL1(d1, s1) FILL1(d2, s2) FILL1(d3, s3)
      FILL1(d4, s4) FILL1(d5, s5) FILL1(d6, s6) FILL1(d7, s7)
    }
    for (; e < E; e += stride){
      int d = dst[e];
      FILL1(d, src[e])
    }
#undef FILL1
  }
}

// g-BN stats (+ lane-parallel f-BN stats): XCD-partitioned nodes (matches fill
// partition's XCD so es/cnt/Q/v are L2-local), cross-node prefetch, unroll 8,
// block-level partial reduction.
__global__ __launch_bounds__(256) void k_gstats(const ushort_t* __restrict__ Pb,
    const ushort_t* __restrict__ Qb, const float* __restrict__ v,
    const float2* __restrict__ uw2, const int* __restrict__ es,
    const int* __restrict__ cnt, float* __restrict__ pstatG, int N, int GB){
  int lane = threadIdx.x & 63;
  int wid = __builtin_amdgcn_readfirstlane(threadIdx.x >> 6);
  int part = ((int)blockIdx.x - GB) & 7;          // same XCD as fill partition
  int Npp = (N + 7) >> 3;
  int lo = part * Npp;
  int hi = lo + Npp; if (hi > N) hi = N;
  int step = (gridDim.x >> 3) << 2;               // waves per partition
  const uint_t* Pu = (const uint_t*)Pb;
  const uint_t* Qu = (const uint_t*)Qb;
  v2f gs = {0.f, 0.f}, gq = {0.f, 0.f};
  float fs = 0.f, fq = 0.f;
  int n = lo + ((blockIdx.x >> 3) << 2) + wid;
  // prefetch node A
  int dnA = 0, sjA = 0; uint_t qA = 0; float vA = 0.f;
  if (n < hi){
    dnA = cnt[n];
    sjA = es[(size_t)n * PAD + lane];
    qA  = Qu[(size_t)n * 64 + lane];
    vA  = v[n];
  }
  while (n < hi){
    int nn = n + step;
    int dnB = 0, sjB = 0; uint_t qB = 0; float vB = 0.f;
    if (nn < hi){                                  // prefetch node B during A's work
      dnB = cnt[nn];
      sjB = es[(size_t)nn * PAD + lane];
      qB  = Qu[(size_t)nn * 64 + lane];
      vB  = v[nn];
    }
    int dn = dnA < PAD ? dnA : PAD;
    int sj = sjA;
    if (lane < dn){
      float2 uw = uw2[sj];
      float t = uw.x + vA;
      fs += t; fq = fmaf(t, t, fq);
    }
    v2f q = bf2(qA);
    int j = 0;
#define GSTAT(p) { v2f y = bf2(p) + q; gs += y; \
                   gq.x = fmaf(y.x, y.x, gq.x); gq.y = fmaf(y.y, y.y, gq.y); }
    for (; j + 7 < dn; j += 8){
      int s0=__shfl(sj,j),   s1=__shfl(sj,j+1), s2=__shfl(sj,j+2), s3=__shfl(sj,j+3);
      int s4=__shfl(sj,j+4), s5=__shfl(sj,j+5), s6=__shfl(sj,j+6), s7=__shfl(sj,j+7);
      uint_t p0=Pu[(size_t)s0*64+lane], p1=Pu[(size_t)s1*64+lane];
      uint_t p2=Pu[(size_t)s2*64+lane], p3=Pu[(size_t)s3*64+lane];
      uint_t p4=Pu[(size_t)s4*64+lane], p5=Pu[(size_t)s5*64+lane];
      uint_t p6=Pu[(size_t)s6*64+lane], p7=Pu[(size_t)s7*64+lane];
      GSTAT(p0) GSTAT(p1) GSTAT(p2) GSTAT(p3)
      GSTAT(p4) GSTAT(p5) GSTAT(p6) GSTAT(p7)
    }
    for (; j + 3 < dn; j += 4){
      int s0=__shfl(sj,j), s1=__shfl(sj,j+1), s2=__shfl(sj,j+2), s3=__shfl(sj,j+3);
      uint_t p0=Pu[(size_t)s0*64+lane], p1=Pu[(size_t)s1*64+lane];
      uint_t p2=Pu[(size_t)s2*64+lane], p3=Pu[(size_t)s3*64+lane];
      GSTAT(p0) GSTAT(p1) GSTAT(p2) GSTAT(p3)
    }
    for (; j < dn; ++j){
      int s0 = __shfl(sj, j);
      uint_t p0 = Pu[(size_t)s0*64+lane];
      GSTAT(p0)
    }
#undef GSTAT
    n = nn; dnA = dnB; sjA = sjB; qA = qB; vA = vB;
  }
  fs = wave_allreduce(fs); fq = wave_allreduce(fq);
  __shared__ float red[4][258];
  red[wid][2*lane]       = gs.x; red[wid][2*lane+1]   = gs.y;
  red[wid][128+2*lane]   = gq.x; red[wid][129+2*lane] = gq.y;
  if (lane == 0){ red[wid][256] = fs; red[wid][257] = fq; }
  __syncthreads();
  for (int c = threadIdx.x; c < 258; c += 256)
    pstatG[(size_t)blockIdx.x * 258 + c] = red[0][c] + red[1][c] + red[2][c] + red[3][c];
}

// fused column-reduce + finalize for g/f BN: block j<128 -> channel j; block 128 -> f
__global__ __launch_bounds__(256) void k_redfin1(const float* __restrict__ pstatG,
    int NB, const float* __restrict__ g_gamma, const float* __restrict__ g_beta,
    const float* __restrict__ f_gamma, const float* __restrict__ f_beta,
    float* __restrict__ fin, long long E){
  int j = blockIdx.x;
  int c1 = (j < 128) ? j : 256;
  int c2 = (j < 128) ? 128 + j : 257;
  double s1 = 0, s2 = 0;
  for (int b = threadIdx.x; b < NB; b += 256){
    const float* pb = pstatG + (size_t)b * 258;
    s1 += (double)pb[c1]; s2 += (double)pb[c2];
  }
  __shared__ double m1[256], m2[256];
  m1[threadIdx.x] = s1; m2[threadIdx.x] = s2;
  __syncthreads();
  for (int o = 128; o; o >>= 1){
    if (threadIdx.x < o){ m1[threadIdx.x] += m1[threadIdx.x + o];
                          m2[threadIdx.x] += m2[threadIdx.x + o]; }
    __syncthreads();
  }
  if (threadIdx.x == 0){
    double m = m1[0] / (double)E;
    double var = m2[0] / (double)E - m * m;
    if (j < 128){
      float sc = (float)((double)g_gamma[j] / sqrt(var + 1e-5));
      fin[2 + j] = sc; fin[130 + j] = g_beta[j] - (float)m * sc;
    } else {
      float sc = (float)((double)f_gamma[0] / sqrt(var + 1e-5));
      fin[0] = sc; fin[1] = f_beta[0] - (float)m * sc;
    }
  }
}

// message pass: XCD-partitioned nodes, cross-node prefetch, unroll 8, deferred
// attention normalization (allreduce off the critical path; single scale at end)
__global__ __launch_bounds__(256) void k_msg(const ushort_t* __restrict__ Pb,
    const ushort_t* __restrict__ Qb, const float* __restrict__ v,
    const float2* __restrict__ uw2, const int* __restrict__ es,
    const int* __restrict__ cnt, const float* __restrict__ fin,
    float* __restrict__ h, float* __restrict__ pstatH, int N, int GB){
  int lane = threadIdx.x & 63;
  int wid = __builtin_amdgcn_readfirstlane(threadIdx.x >> 6);
  int part = ((int)blockIdx.x - GB) & 7;
  int Npp = (N + 7) >> 3;
  int lo = part * Npp;
  int hi = lo + Npp; if (hi > N) hi = N;
  int step = (gridDim.x >> 3) << 2;
  const uint_t* Pu = (const uint_t*)Pb;
  const uint_t* Qu = (const uint_t*)Qb;
  float fsc = fin[0], fsh = fin[1];
  v2f gsc = {fin[2 + 2*lane], fin[3 + 2*lane]};
  v2f gsh = {fin[130 + 2*lane], fin[131 + 2*lane]};
  v2f hs = {0.f, 0.f}, hq = {0.f, 0.f};
  int n = lo + ((blockIdx.x >> 3) << 2) + wid;
  int dnA = 0, sjA = 0; uint_t qA = 0; float vA = 0.f;
  if (n < hi){
    dnA = cnt[n];
    sjA = es[(size_t)n * PAD + lane];
    qA  = Qu[(size_t)n * 64 + lane];
    vA  = v[n];
  }
  while (n < hi){
    int nn = n + step;
    int dnB = 0, sjB = 0; uint_t qB = 0; float vB = 0.f;
    if (nn < hi){
      dnB = cnt[nn];
      sjB = es[(size_t)nn * PAD + lane];
      qB  = Qu[(size_t)nn * 64 + lane];
      vB  = v[nn];
    }
    int dn = dnA < PAD ? dnA : PAD;
    int sj = sjA;
    float wj = 0.f;
    if (lane < dn){
      float2 uw = uw2[sj];
      float tt = fmaf(uw.x + vA, fsc, fsh);
      float sl = tt * __builtin_amdgcn_rcpf(1.f + __expf(-tt));
      wj = uw.y * __expf(sl);
    }
    v2f q = bf2(qA);
    v2f acc = {0.f, 0.f};
    int j = 0;
#define EDGE(p,a) { v2f y = (bf2(p) + q) * gsc + gsh; \
      float e0 = __expf(-y.x), e1 = __expf(-y.y); \
      float d0 = 1.f + e0, d1 = 1.f + e1; \
      float r = __builtin_amdgcn_rcpf(d0 * d1) * a; \
      acc.x = fmaf(y.x * d1, r, acc.x); acc.y = fmaf(y.y * d0, r, acc.y); }
    for (; j + 7 < dn; j += 8){
      int s0=__shfl(sj,j),   s1=__shfl(sj,j+1), s2=__shfl(sj,j+2), s3=__shfl(sj,j+3);
      int s4=__shfl(sj,j+4), s5=__shfl(sj,j+5), s6=__shfl(sj,j+6), s7=__shfl(sj,j+7);
      float a0=__shfl(wj,j),   a1=__shfl(wj,j+1), a2=__shfl(wj,j+2), a3=__shfl(wj,j+3);
      float a4=__shfl(wj,j+4), a5=__shfl(wj,j+5), a6=__shfl(wj,j+6), a7=__shfl(wj,j+7);
      uint_t p0=Pu[(size_t)s0*64+lane], p1=Pu[(size_t)s1*64+lane];
      uint_t p2=Pu[(size_t)s2*64+lane], p3=Pu[(size_t)s3*64+lane];
      uint_t p4=Pu[(size_t)s4*64+lane], p5=Pu[(size_t)s5*64+lane];
      uint_t p6=Pu[(size_t)s6*64+lane], p7=Pu[(size_t)s7*64+lane];
      EDGE(p0,a0) EDGE(p1,a1) EDGE(p2,a2) EDGE(p3,a3)
      EDGE(p4,a4) EDGE(p5,a5) EDGE(p6,a6) EDGE(p7,a7)
    }
    for (; j + 3 < dn; j += 4){
      int s0=__shfl(sj,j), s1=__shfl(sj,j+1), s2=__shfl(sj,j+2), s3=__shfl(sj,j+3);
      float a0=__shfl(wj,j), a1=__shfl(wj,j+1), a2=__shfl(wj,j+2), a3=__shfl(wj,j+3);
      uint_t p0=Pu[(size_t)s0*64+lane], p1=Pu[(size_t)s1*64+lane];
      uint_t p2=Pu[(size_t)s2*64+lane], p3=Pu[(size_t)s3*64+lane];
      EDGE(p0,a0) EDGE(p1,a1) EDGE(p2,a2) EDGE(p3,a3)
    }
    for (; j < dn; ++j){
      int s0 = __shfl(sj, j);
      float a0 = __shfl(wj, j);
      uint_t p0 = Pu[(size_t)s0*64+lane];
      EDGE(p0,a0)
    }
#undef EDGE
    // deferred normalization: h = (sum_j w_j z_j) / (sum_j w_j)
    float sw = wave_allreduce(wj);
    float rs = (dn > 0) ? (1.f / sw) : 0.f;
    acc.x *= rs; acc.y *= rs;
    *(float2*)&h[(size_t)n * 128 + 2*lane] = make_float2(acc.x, acc.y);
    hs += acc; hq += acc * acc;
    n = nn; dnA = dnB; sjA = sjB; qA = qB; vA = vB;
  }
  __shared__ float red[4][256];
  red[wid][2*lane]       = hs.x; red[wid][2*lane+1]   = hs.y;
  red[wid][128+2*lane]   = hq.x; red[wid][129+2*lane] = hq.y;
  __syncthreads();
  int c = threadIdx.x;
  pstatH[(size_t)blockIdx.x * 256 + c] = red[0][c] + red[1][c] + red[2][c] + red[3][c];
}

// fused column-reduce + finalize for node BN: block j -> channel j
__global__ __launch_bounds__(256) void k_redfin2(const float* __restrict__ pstatH,
    int NB, const float* __restrict__ n_gamma, const float* __restrict__ n_beta,
    float* __restrict__ fin, int N){
  int j = blockIdx.x;
  double s1 = 0, s2 = 0;
  for (int b = threadIdx.x; b < NB; b += 256){
    const float* pb = pstatH + (size_t)b * 256;
    s1 += (double)pb[j]; s2 += (double)pb[128 + j];
  }
  __shared__ double m1[256], m2[256];
  m1[threadIdx.x] = s1; m2[threadIdx.x] = s2;
  __syncthreads();
  for (int o = 128; o; o >>= 1){
    if (threadIdx.x < o){ m1[threadIdx.x] += m1[threadIdx.x + o];
                          m2[threadIdx.x] += m2[threadIdx.x + o]; }
    __syncthreads();
  }
  if (threadIdx.x == 0){
    double m = m1[0] / (double)N;
    double var = m2[0] / (double)N - m * m;
    float sc = (float)((double)n_gamma[j] / sqrt(var + 1e-5));
    fin[258 + j] = sc; fin[386 + j] = n_beta[j] - (float)m * sc;
  }
}

__global__ __launch_bounds__(256) void k_out(const float* __restrict__ h,
    const float* __restrict__ x, const float* __restrict__ fin,
    float* __restrict__ out, int total4){
  int i = blockIdx.x * 256 + threadIdx.x;
  if (i >= total4) return;
  const float4* h4 = (const float4*)h; const float4* x4 = (const float4*)x;
  float4 hv = h4[i], xv = x4[i];
  int c = (i * 4) & 127;
  float4 o;
  o.x = fmaf(hv.x, fin[258 + c],     fin[386 + c])     + xv.x;
  o.y = fmaf(hv.y, fin[258 + c + 1], fin[386 + c + 1]) + xv.y;
  o.z = fmaf(hv.z, fin[258 + c + 2], fin[386 + c + 2]) + xv.z;
  o.w = fmaf(hv.w, fin[258 + c + 3], fin[386 + c + 3]) + xv.w;
  ((float4*)out)[i] = o;
}

extern "C" void kernel_launch(void* const* d_in, const int* in_sizes, int n_in,
                              void* d_out, int out_size, void* d_ws, size_t ws_size,
                              hipStream_t stream){
  const float* x       = (const float*)d_in[0];
  const float* weight  = (const float*)d_in[1];
  const int*   src     = (const int*)d_in[2];
  const int*   dst     = (const int*)d_in[3];
  const float* Wf      = (const float*)d_in[4];
  // d_in[5] = bf : cancels inside BatchNorm — unused
  const float* f_gamma = (const float*)d_in[6];
  const float* f_beta  = (const float*)d_in[7];
  const float* Wg      = (const float*)d_in[8];
  // d_in[9] = bg : cancels inside BatchNorm — unused
  const float* g_gamma = (const float*)d_in[10];
  const float* g_beta  = (const float*)d_in[11];
  const float* n_gamma = (const float*)d_in[12];
  const float* n_beta  = (const float*)d_in[13];
  float* out = (float*)d_out;

  int N = in_sizes[0] / HDIM;
  int E = in_sizes[2];

  char* ws = (char*)d_ws;
  size_t off = 0;
  auto alloc = [&](size_t bytes)->char*{
    char* p = ws + off; off = (off + bytes + 255) & ~(size_t)255; return p;
  };
  ushort_t* Pb    = (ushort_t*)alloc((size_t)N * HDIM * 2);
  ushort_t* Qb    = (ushort_t*)alloc((size_t)N * HDIM * 2);
  float* h        = (float*)alloc((size_t)N * HDIM * 4);
  float* v        = (float*)alloc((size_t)N * 4);
  float2* uw2     = (float2*)alloc((size_t)N * 8);
  int* es         = (int*)alloc((size_t)N * PAD * 4);
  ushort_t* W2t   = (ushort_t*)alloc((size_t)272 * 128 * 2);
  int* cnt        = (int*)alloc((size_t)N * 4);
  const int NWB = 2048;              // blocks for gstats/msg (4 waves each)
  const int NB  = NWB;               // one partial row per block
  float*  pstatG = (float*)alloc((size_t)NB * 258 * 4);
  float*  pstatH = (float*)alloc((size_t)NB * 256 * 4);
  float*  fin    = (float*)alloc(514 * 4);

  int GB = (N + 31) / 32;            // gemm blocks (2 strips of 16 rows each)
  const int FB = 1024;               // fill blocks (8 partitions x 128 chunks; ~24 iters/thread -> 3 full unroll-8 rounds)

  k_wpack   <<<272 + (N + 127) / 128, 128, 0, stream>>>(Wg, Wf, W2t, cnt, N);
  k_gemmfill<<<GB + FB, 256, 0, stream>>>(x, W2t, weight, Pb, Qb, v, uw2,
                                          src, dst, cnt, es, N, E, GB);
  k_gstats  <<<NWB, 256, 0, stream>>>(Pb, Qb, v, uw2, es, cnt, pstatG, N, GB);
  k_redfin1 <<<129, 256, 0, stream>>>(pstatG, NB, g_gamma, g_beta, f_gamma, f_beta, fin, (long long)E);
  k_msg     <<<NWB, 256, 0, stream>>>(Pb, Qb, v, uw2, es, cnt, fin, h, pstatH, N, GB);
  k_redfin2 <<<128, 256, 0, stream>>>(pstatH, NB, n_gamma, n_beta, fin, N);
  k_out     <<<(N * HDIM / 4 + 255) / 256, 256, 0, stream>>>(h, x, fin, out, N * HDIM / 4);
}